// Round 9
// baseline (126.706 us; speedup 1.0000x reference)
//
#include <hip/hip_runtime.h>
#include <hip/hip_bf16.h>

#define NPOS 2744      // 14^3
#define BB 4
#define BNTOT (BB*NPOS)   // 10976
#define RELVOL 19683   // 27^3
#define EROWS 19696        // padded elems per k-row (even, >= 19686)
#define TBLE (16*EROWS)    // 315136 elems per table copy
#define NRT 196            // (zm,ym) row-tiles, 16 kslots each (x=0..13 real)
#define NV2 (NRT*2*64)     // 25088 vfrag2 entries
#define N4T 1024           // lc

typedef __bf16 bf16x8 __attribute__((ext_vector_type(8)));
typedef float f32x16 __attribute__((ext_vector_type(16)));

// ---- workspace layout (bytes) ----
#define WS_Q  0u           // f32 [4][64][2744]
#define WS_K  2809856u     // f32 [4][16][2744]  (dead after k_sl; vfrag2 aliases it)
#define WS_V  3512320u     // f32 [4][16][2744]
#define WS_ST 4214784u     // f32 [160] scale/shift
#define WS_LA 4216192u     // f32 [1088] lc accum: [4][16][17]
#define WS_LC 4220544u     // f32 [4][16][16]
#define WS_E2 4224640u     // u16 [2][16][EROWS] dup bf16 E table, k-MAJOR (copyB shifted by 1)
#define WS_VF WS_K         // uint4 [196][2][64] v B-fragments, x-row tiling

__device__ inline unsigned short f2bf(float f) {
  unsigned int u = __float_as_uint(f);
  return (unsigned short)((u + 0x7fffu + ((u >> 16) & 1u)) >> 16);
}

// ---------------- P1: qkv projections (blocks 0..515) + dup E-table build + la-zero (516..823) ----------------
__global__ __launch_bounds__(256) void k_qkv(const float* __restrict__ x,
    const float* __restrict__ Wq, const float* __restrict__ Wk, const float* __restrict__ Wv,
    const float* __restrict__ rpe,
    float* __restrict__ qws, float* __restrict__ kws, float* __restrict__ vws,
    unsigned short* __restrict__ ebf, float* __restrict__ la) {
  int bid = blockIdx.x;
  int tid = threadIdx.x;
  if (bid >= 516) {
    int bid2 = bid - 516;                      // 0..307
    if (bid2 == 0 && tid < 272) ((float4*)la)[tid] = make_float4(0.f, 0.f, 0.f, 0.f);
    const int TOT = 2 * TBLE;                  // both copies
    for (int e = bid2 * 256 + tid; e < TOT; e += 308 * 256) {
      int cp = (e >= TBLE) ? 1 : 0;
      int c = e - cp * TBLE;
      int k = c / EROWS;
      int iPos = c - k * EROWS;
      int j = iPos + cp;                       // copyB[i] = T[i+1]
      float val = (j < RELVOL) ? rpe[j * 16 + k] : 0.f;
      ebf[e] = f2bf(val);
    }
    return;
  }
  int cg = bid % 12, nb = bid / 12;
  int gid = nb * 256 + tid;
  if (gid >= BNTOT) return;
  int b = gid / NPOS, n = gid - b * NPOS;
  const float* xp = x + (size_t)b * 64 * NPOS + n;
  int ch0 = cg * 8;
  const float* wbase;
  float* obase;
  if (ch0 < 64)      { wbase = Wq + ch0 * 64;        obase = qws + ((size_t)b * 64 + ch0) * NPOS + n; }
  else if (ch0 < 80) { wbase = Wk + (ch0 - 64) * 64; obase = kws + ((size_t)b * 16 + (ch0 - 64)) * NPOS + n; }
  else               { wbase = Wv + (ch0 - 80) * 64; obase = vws + ((size_t)b * 16 + (ch0 - 80)) * NPOS + n; }

  float acc[8];
#pragma unroll
  for (int j = 0; j < 8; ++j) acc[j] = 0.f;
  for (int c = 0; c < 64; c += 4) {
    float x0 = xp[(c + 0) * NPOS], x1 = xp[(c + 1) * NPOS];
    float x2 = xp[(c + 2) * NPOS], x3 = xp[(c + 3) * NPOS];
#pragma unroll
    for (int j = 0; j < 8; ++j) {
      float4 w = *(const float4*)(wbase + j * 64 + c);
      acc[j] += w.x * x0 + w.y * x1 + w.z * x2 + w.w * x3;
    }
  }
#pragma unroll
  for (int j = 0; j < 8; ++j) obase[(size_t)j * NPOS] = acc[j];
}

// ---------------- P2: BN stats+finalize (blocks 0..79) | lambda_c partials (80..335) ----------------
__global__ __launch_bounds__(256) void k_sl(const float* __restrict__ qws,
    const float* __restrict__ kws, const float* __restrict__ vws,
    const float* __restrict__ gq, const float* __restrict__ bq,
    const float* __restrict__ gv, const float* __restrict__ bv,
    float* __restrict__ st, float* __restrict__ lcacc) {
  int bid = blockIdx.x;
  int tid = threadIdx.x;
  int wid = tid >> 6;
  __shared__ float red[17][4];
  if (bid < 80) {
    int ch = bid;
    const float* p = (ch < 64) ? (qws + (size_t)ch * NPOS) : (vws + (size_t)(ch - 64) * NPOS);
    size_t pstride = (ch < 64) ? (size_t)64 * NPOS : (size_t)16 * NPOS;
    float s = 0.f, ss = 0.f;
    for (int b = 0; b < 4; ++b) {
      const float* pp = p + b * pstride;
      for (int n = tid; n < NPOS; n += 256) { float v = pp[n]; s += v; ss += v * v; }
    }
#pragma unroll
    for (int o = 32; o > 0; o >>= 1) { s += __shfl_xor(s, o, 64); ss += __shfl_xor(ss, o, 64); }
    if ((tid & 63) == 0) { red[0][wid] = s; red[1][wid] = ss; }
    __syncthreads();
    if (tid == 0) {
      float S = red[0][0] + red[0][1] + red[0][2] + red[0][3];
      float SS = red[1][0] + red[1][1] + red[1][2] + red[1][3];
      float mean = S / (float)BNTOT;
      float var = SS / (float)BNTOT - mean * mean;
      float inv = rsqrtf(var + 1e-5f);
      float g, be;
      if (ch < 64) { g = gq[ch]; be = bq[ch]; } else { g = gv[ch - 64]; be = bv[ch - 64]; }
      float sc = g * inv, sh = be - mean * sc;
      if (ch < 64) { st[ch] = sc; st[64 + ch] = sh; }
      else { st[128 + (ch - 64)] = sc; st[144 + (ch - 64)] = sh; }
    }
  } else {
    int bid2 = bid - 80;
    int b = bid2 >> 6, kc = (bid2 >> 2) & 15, seg = bid2 & 3;
    const float* kp = kws + ((size_t)b * 16 + kc) * NPOS;
    const float* vp = vws + (size_t)b * 16 * NPOS;
    float s = 0.f, acc[16];
#pragma unroll
    for (int v = 0; v < 16; ++v) acc[v] = 0.f;
    int m0 = seg * 686;
    for (int m = m0 + tid; m < m0 + 686; m += 256) {
      float e = __expf(kp[m]);
      s += e;
#pragma unroll
      for (int v = 0; v < 16; ++v) acc[v] += e * vp[(size_t)v * NPOS + m];
    }
#pragma unroll
    for (int o = 32; o > 0; o >>= 1) {
      s += __shfl_xor(s, o, 64);
#pragma unroll
      for (int v = 0; v < 16; ++v) acc[v] += __shfl_xor(acc[v], o, 64);
    }
    if ((tid & 63) == 0) { red[16][wid] = s; for (int v = 0; v < 16; ++v) red[v][wid] = acc[v]; }
    __syncthreads();
    if (tid < 17) {
      float tot = red[tid][0] + red[tid][1] + red[tid][2] + red[tid][3];
      atomicAdd(lcacc + ((size_t)b * 16 + kc) * 17 + tid, tot);
    }
  }
}

// ---------------- P3: vfrag2 (x-row tiling) + lc finalize (102 blocks * 256 = 26112) ----------------
__global__ __launch_bounds__(256) void k_conv2(const float* __restrict__ vws,
    const float* __restrict__ st, const float* __restrict__ lcacc,
    uint4* __restrict__ vfrag, float* __restrict__ lc) {
  int idx = blockIdx.x * 256 + threadIdx.x;
  if (idx < NV2) {
    int rt = idx >> 7; int r = idx & 127;
    int ct = r >> 6, l = r & 63;
    int zm = rt / 14, ym = rt - zm * 14;
    int kh = l >> 5;
    int b = ct * 2 + ((l >> 4) & 1), v = l & 15;
    int mrow = zm * 196 + ym * 14;
    float sc = st[128 + v], sh = st[144 + v];
    unsigned int wds[4];
#pragma unroll
    for (int i = 0; i < 4; ++i) {
      int x0 = kh * 8 + 2 * i, x1 = x0 + 1;
      float f0 = 0.f, f1 = 0.f;
      if (x0 < 14) f0 = vws[((size_t)b * 16 + v) * NPOS + mrow + x0] * sc + sh;
      if (x1 < 14) f1 = vws[((size_t)b * 16 + v) * NPOS + mrow + x1] * sc + sh;
      wds[i] = (unsigned int)f2bf(f0) | ((unsigned int)f2bf(f1) << 16);
    }
    vfrag[(rt * 2 + ct) * 64 + l] = make_uint4(wds[0], wds[1], wds[2], wds[3]);
  } else if (idx < NV2 + N4T) {
    int t = idx - NV2;
    int b = t >> 8, kc = (t >> 4) & 15, v = t & 15;
    const float* la = lcacc + ((size_t)b * 16 + kc) * 17;
    float S = la[16];
    lc[((size_t)b * 16 + kc) * 16 + v] = st[128 + v] * (la[v] / S) + st[144 + v];
  }
}

// ---------------- P4: main lambda_p MFMA kernel (direct A-gather, no transpose MFMA) ----------------
// 686 blocks * 256 thr (4 waves). Block g owns n-quad {4g..4g+3} as 2 n-pairs P,Q.
// Wave w = m-quarter: rt in [w*49, w*49+49). Per rt (one (zm,ym) x-row, 16 kslots):
// lane l = (kh=l>>5, nsel=(l>>4)&1, kq=l&15) loads its A fragment DIRECTLY from the
// dup bf16 k-major E table (parity-aligned dwordx4), B from vfrag2; 4 MFMAs (2np x 2ct).
__global__ __launch_bounds__(256, 2) void k_lam(const unsigned short* __restrict__ ebf,
    const uint4* __restrict__ vfrag, const float* __restrict__ qws,
    const float* __restrict__ st, const float* __restrict__ lc, float* __restrict__ out) {
  __shared__ float red[8192];   // 32 KB reduction scratch
  int tid = threadIdx.x;
  int w = tid >> 6, l = tid & 63;
  int g = blockIdx.x;
  int arow = l & 31;
  int nsel = arow >> 4, kq = arow & 15;
  int kh = l >> 5;

  // element-base for the two n's this lane serves (np P: n=4g+nsel; np Q: n=4g+2+nsel)
  int ebase[2];
#pragma unroll
  for (int sq = 0; sq < 2; ++sq) {
    int n = g * 4 + sq * 2 + nsel;
    int zn = n / 196; int t0 = n - zn * 196; int yn = t0 / 14; int xn = t0 - yn * 14;
    ebase[sq] = kq * EROWS + (13 - zn) * 729 + (13 - yn) * 27 + (13 - xn) + kh * 8;
  }
  int ebP = ebase[0], ebQ = ebase[1];

  f32x16 acc0, acc1, acc2, acc3;
#pragma unroll
  for (int i = 0; i < 16; ++i) { acc0[i] = 0.f; acc1[i] = 0.f; acc2[i] = 0.f; acc3[i] = 0.f; }

  int rt0 = w * 49;
  // prologue loads for rt0
  uint4 AP, AQ, B0, B1;
  {
    int zm = rt0 / 14, ym = rt0 - zm * 14;
    int ro = zm * 729 + ym * 27;
    int sP = ebP + ro, sQ = ebQ + ro;
    AP = *(const uint4*)(ebf + (sP & ~1) + (sP & 1) * TBLE);
    AQ = *(const uint4*)(ebf + (sQ & ~1) + (sQ & 1) * TBLE);
    const uint4* vf = vfrag + (size_t)(rt0 * 2) * 64 + l;
    B0 = vf[0]; B1 = vf[64];
  }

  for (int d = 0; d < 49; ++d) {
    int rt1 = rt0 + d + ((d < 48) ? 1 : 0);
    int zm = rt1 / 14, ym = rt1 - zm * 14;
    int ro = zm * 729 + ym * 27;
    int sP = ebP + ro, sQ = ebQ + ro;
    uint4 nAP = *(const uint4*)(ebf + (sP & ~1) + (sP & 1) * TBLE);
    uint4 nAQ = *(const uint4*)(ebf + (sQ & ~1) + (sQ & 1) * TBLE);
    const uint4* vf = vfrag + (size_t)(rt1 * 2) * 64 + l;
    uint4 nB0 = vf[0], nB1 = vf[64];
    __builtin_amdgcn_s_setprio(1);
    acc0 = __builtin_amdgcn_mfma_f32_32x32x16_bf16(
        __builtin_bit_cast(bf16x8, AP), __builtin_bit_cast(bf16x8, B0), acc0, 0, 0, 0);
    acc1 = __builtin_amdgcn_mfma_f32_32x32x16_bf16(
        __builtin_bit_cast(bf16x8, AP), __builtin_bit_cast(bf16x8, B1), acc1, 0, 0, 0);
    acc2 = __builtin_amdgcn_mfma_f32_32x32x16_bf16(
        __builtin_bit_cast(bf16x8, AQ), __builtin_bit_cast(bf16x8, B0), acc2, 0, 0, 0);
    acc3 = __builtin_amdgcn_mfma_f32_32x32x16_bf16(
        __builtin_bit_cast(bf16x8, AQ), __builtin_bit_cast(bf16x8, B1), acc3, 0, 0, 0);
    __builtin_amdgcn_s_setprio(0);
    AP = nAP; AQ = nAQ; B0 = nB0; B1 = nB1;
  }

  // ---- tree reduction across 4 m-quarter waves ----
  if (w >= 2) {
    float* r0 = red + (w - 2) * 4096;
#pragma unroll
    for (int r = 0; r < 16; ++r) {
      r0[r * 64 + l] = acc0[r];         r0[1024 + r * 64 + l] = acc1[r];
      r0[2048 + r * 64 + l] = acc2[r];  r0[3072 + r * 64 + l] = acc3[r];
    }
  }
  __syncthreads();
  if (w < 2) {
    const float* r0 = red + w * 4096;
#pragma unroll
    for (int r = 0; r < 16; ++r) {
      acc0[r] += r0[r * 64 + l];        acc1[r] += r0[1024 + r * 64 + l];
      acc2[r] += r0[2048 + r * 64 + l]; acc3[r] += r0[3072 + r * 64 + l];
    }
  }
  __syncthreads();
  if (w == 1) {
#pragma unroll
    for (int r = 0; r < 16; ++r) {
      red[r * 64 + l] = acc0[r];         red[1024 + r * 64 + l] = acc1[r];
      red[2048 + r * 64 + l] = acc2[r];  red[3072 + r * 64 + l] = acc3[r];
    }
  }
  __syncthreads();
  if (w == 0) {
#pragma unroll
    for (int r = 0; r < 16; ++r) {
      acc0[r] += red[r * 64 + l];        acc1[r] += red[1024 + r * 64 + l];
      acc2[r] += red[2048 + r * 64 + l]; acc3[r] += red[3072 + r * 64 + l];
    }
    int sig = kh;
    int bsel = (l >> 4) & 1, v = l & 15;
#pragma unroll
    for (int sq = 0; sq < 2; ++sq) {
      int np = g * 2 + sq;
#pragma unroll
      for (int ct = 0; ct < 2; ++ct) {
        int b = ct * 2 + bsel;
        float lam[16];
#pragma unroll
        for (int r = 0; r < 16; ++r) {
          int kk = (r & 3) + 4 * sig + 8 * ((r >> 2) & 1);
          float av = sq ? (ct ? acc3[r] : acc2[r]) : (ct ? acc1[r] : acc0[r]);
          lam[r] = av + lc[((size_t)b * 16 + kk) * 16 + v];
        }
#pragma unroll
        for (int ns = 0; ns < 2; ++ns) {
          int n = np * 2 + ns;
#pragma unroll
          for (int h = 0; h < 4; ++h) {
            float part = 0.f;
#pragma unroll
            for (int rr = 0; rr < 8; ++rr) {
              int kk = (rr & 3) + 4 * sig + 8 * ((rr >> 2) & 1);
              int ch = h * 16 + kk;
              float qv = qws[((size_t)b * 64 + ch) * NPOS + n] * st[ch] + st[64 + ch];
              part += qv * lam[ns * 8 + rr];
            }
            part += __shfl_xor(part, 32, 64);
            if (sig == 0) out[((size_t)b * 64 + h * 16 + v) * NPOS + n] = part;
          }
        }
      }
    }
  }
}

extern "C" void kernel_launch(void* const* d_in, const int* in_sizes, int n_in,
                              void* d_out, int out_size, void* d_ws, size_t ws_size,
                              hipStream_t stream) {
  const float* x   = (const float*)d_in[0];
  const float* Wq  = (const float*)d_in[1];
  const float* Wk  = (const float*)d_in[2];
  const float* Wv  = (const float*)d_in[3];
  const float* rpe = (const float*)d_in[4];
  const float* gq  = (const float*)d_in[5];
  const float* bq  = (const float*)d_in[6];
  const float* gv  = (const float*)d_in[7];
  const float* bv  = (const float*)d_in[8];
  float* out = (float*)d_out;
  char* ws = (char*)d_ws;
  float* qws = (float*)(ws + WS_Q);
  float* kws = (float*)(ws + WS_K);
  float* vws = (float*)(ws + WS_V);
  float* st  = (float*)(ws + WS_ST);
  float* la  = (float*)(ws + WS_LA);
  float* lcp = (float*)(ws + WS_LC);
  unsigned short* ebf = (unsigned short*)(ws + WS_E2);
  uint4* vfrag = (uint4*)(ws + WS_VF);

  k_qkv<<<824, 256, 0, stream>>>(x, Wq, Wk, Wv, rpe, qws, kws, vws, ebf, la);
  k_sl<<<336, 256, 0, stream>>>(qws, kws, vws, gq, bq, gv, bv, st, la);
  k_conv2<<<102, 256, 0, stream>>>(vws, st, la, vfrag, lcp);
  k_lam<<<686, 256, 0, stream>>>(ebf, vfrag, qws, st, lcp, out);
}